// Round 6
// baseline (1765.576 us; speedup 1.0000x reference)
//
#include <hip/hip_runtime.h>
#include <math.h>

#define Bn   2048
#define Hd   512
#define H3   1536
#define OUTD 256
#define Nn   32768
#define TMAX 48
#define Kd   512

typedef __attribute__((ext_vector_type(8))) short short8v;
typedef __attribute__((ext_vector_type(4))) float float4v;

__device__ __forceinline__ float sigm(float x) { return 1.0f / (1.0f + __expf(-x)); }

__device__ __forceinline__ short f2bf(float v) {
    union { float f; unsigned u; } a; a.f = v;
    unsigned r = a.u + 0x7fffu + ((a.u >> 16) & 1u);
    return (short)(r >> 16);
}
__device__ __forceinline__ float bf2f(short s) {
    union { float f; unsigned u; } a; a.u = ((unsigned)(unsigned short)s) << 16;
    return a.f;
}

#define MF(acc, A, B) acc = __builtin_amdgcn_mfma_f32_16x16x32_bf16(A, B, acc, 0, 0, 0)

// ---------- prologue: counts/starts + count-descending sort + active[] ----------
__global__ void prologue(const int* __restrict__ psi, int* __restrict__ perm,
                         int* __restrict__ startsP, int* __restrict__ active) {
    __shared__ int hist[64];
    __shared__ int base[64];
    __shared__ int cur[64];
    __shared__ int cnt_s[Bn];
    __shared__ int start_s[Bn];
    const int tid = threadIdx.x;
    if (tid < 64) { hist[tid] = 0; cur[tid] = 0; }
    __syncthreads();
    for (int b = tid; b < Bn; b += 1024) {
        int lo = 0, hi = Nn;
        while (lo < hi) { int mid = (lo + hi) >> 1; if (psi[mid] < b) lo = mid + 1; else hi = mid; }
        int lb = lo;
        lo = 0; hi = Nn;
        while (lo < hi) { int mid = (lo + hi) >> 1; if (psi[mid] <= b) lo = mid + 1; else hi = mid; }
        int c = lo - lb;
        cnt_s[b] = c;
        start_s[b] = lb;
        atomicAdd(&hist[min(c, 63)], 1);
    }
    __syncthreads();
    if (tid == 0) {
        base[63] = 0;
        for (int c = 62; c >= 0; --c) base[c] = base[c + 1] + hist[c + 1];
    }
    __syncthreads();
    if (tid < 64) active[tid] = base[tid];
    for (int b = tid; b < Bn; b += 1024) {
        int c = min(cnt_s[b], 63);
        int pos = base[c] + atomicAdd(&cur[c], 1);
        perm[pos] = b;
        startsP[pos] = start_s[b];
    }
}

// ---------- split fp32 -> bf16 hi + lo ----------
__global__ __launch_bounds__(256)
void split_kern(const float* __restrict__ src, short* __restrict__ hi,
                short* __restrict__ lo, int n) {
    int i = (blockIdx.x * 256 + threadIdx.x) * 4;
    if (i >= n) return;
    float4 v = *(const float4*)&src[i];
    float vv[4] = {v.x, v.y, v.z, v.w};
    short h4[4], l4[4];
    #pragma unroll
    for (int c = 0; c < 4; ++c) {
        short h = f2bf(vv[c]);
        h4[c] = h;
        l4[c] = f2bf(vv[c] - bf2f(h));
    }
    *(short4*)&hi[i] = make_short4(h4[0], h4[1], h4[2], h4[3]);
    *(short4*)&lo[i] = make_short4(l4[0], l4[1], l4[2], l4[3]);
}

// split x rows permuted into compact order
__global__ __launch_bounds__(256)
void split_perm(const float* __restrict__ src, const int* __restrict__ perm,
                short* __restrict__ hi, short* __restrict__ lo) {
    int i = (blockIdx.x * 256 + threadIdx.x) * 4;       // over 2048*512
    int row = i >> 9, col = i & 511;
    int srow = perm[row];
    float4 v = *(const float4*)&src[(size_t)srow * 512 + col];
    float vv[4] = {v.x, v.y, v.z, v.w};
    short h4[4], l4[4];
    #pragma unroll
    for (int c = 0; c < 4; ++c) {
        short h = f2bf(vv[c]);
        h4[c] = h;
        l4[c] = f2bf(vv[c] - bf2f(h));
    }
    *(short4*)&hi[i] = make_short4(h4[0], h4[1], h4[2], h4[3]);
    *(short4*)&lo[i] = make_short4(l4[0], l4[1], l4[2], l4[3]);
}

// pack W1rz[1024][1024] = [Wih1_rz | Whh1_rz] split hi/lo
__global__ __launch_bounds__(256)
void pack_w1rz(const float* __restrict__ Wih1, const float* __restrict__ Whh1,
               short* __restrict__ hi, short* __restrict__ lo) {
    int i = (blockIdx.x * 256 + threadIdx.x) * 4;       // over 1024*1024
    int orow = i >> 10, k = i & 1023;
    const float* s = (k < 512) ? &Wih1[(size_t)orow * 512 + k]
                               : &Whh1[(size_t)orow * 512 + (k - 512)];
    float4 v = *(const float4*)s;
    float vv[4] = {v.x, v.y, v.z, v.w};
    short h4[4], l4[4];
    #pragma unroll
    for (int c = 0; c < 4; ++c) {
        short h = f2bf(vv[c]);
        h4[c] = h;
        l4[c] = f2bf(vv[c] - bf2f(h));
    }
    *(short4*)&hi[i] = make_short4(h4[0], h4[1], h4[2], h4[3]);
    *(short4*)&lo[i] = make_short4(l4[0], l4[1], l4[2], l4[3]);
}

__global__ __launch_bounds__(256)
void zero4(short* __restrict__ a, short* __restrict__ b,
           short* __restrict__ c, short* __restrict__ d, int n) {
    int i = (blockIdx.x * 256 + threadIdx.x) * 4;
    if (i >= n) return;
    short4 z = make_short4(0, 0, 0, 0);
    *(short4*)&a[i] = z; *(short4*)&b[i] = z;
    *(short4*)&c[i] = z; *(short4*)&d[i] = z;
}

// ---------- MFMA 128x128 tile core (round-5 proven): C = A @ W^T (+bias) ----------
template<bool SPLIT_A>
__device__ __forceinline__ void gemm_tile(
    const short* __restrict__ Ahi, const short* __restrict__ Alo,
    const short* __restrict__ Whi, const short* __restrict__ Wlo,
    const float* __restrict__ bias, float* __restrict__ C,
    int m0, int n0, int ldC, short* lds) {
    short* ldsAhi = lds;
    short* ldsAlo = lds + 4096;
    short* ldsBhi = lds + 8192;
    short* ldsBlo = lds + 12288;
    const int tid = threadIdx.x;
    const int wid = tid >> 6, lane = tid & 63;
    const int wm = wid >> 1, wn = wid & 1;
    const int oi0 = tid * 2, oi1 = tid * 2 + 1;
    const int r0 = oi0 >> 2, c0 = oi0 & 3;
    const int r1 = oi1 >> 2, c1 = oi1 & 3;
    const int w0 = ((r0 >> 4) * 64 + (r0 & 15) + (c0 << 4)) * 8;
    const int w1 = ((r1 >> 4) * 64 + (r1 & 15) + (c1 << 4)) * 8;

    float4v acc[4][4] = {};
    int4 ah0, ah1, al0, al1, bh0, bh1, bl0, bl1;

#define LOADK(kt) do { const int k0 = (kt) * 32; \
    ah0 = *(const int4*)&Ahi[(size_t)(m0 + r0) * Kd + k0 + c0 * 8]; \
    ah1 = *(const int4*)&Ahi[(size_t)(m0 + r1) * Kd + k0 + c1 * 8]; \
    if constexpr (SPLIT_A) { \
        al0 = *(const int4*)&Alo[(size_t)(m0 + r0) * Kd + k0 + c0 * 8]; \
        al1 = *(const int4*)&Alo[(size_t)(m0 + r1) * Kd + k0 + c1 * 8]; } \
    bh0 = *(const int4*)&Whi[(size_t)(n0 + r0) * Kd + k0 + c0 * 8]; \
    bh1 = *(const int4*)&Whi[(size_t)(n0 + r1) * Kd + k0 + c1 * 8]; \
    bl0 = *(const int4*)&Wlo[(size_t)(n0 + r0) * Kd + k0 + c0 * 8]; \
    bl1 = *(const int4*)&Wlo[(size_t)(n0 + r1) * Kd + k0 + c1 * 8]; } while (0)

    LOADK(0);
    for (int kt = 0; kt < 16; ++kt) {
        __syncthreads();
        *(int4*)&ldsAhi[w0] = ah0; *(int4*)&ldsAhi[w1] = ah1;
        if constexpr (SPLIT_A) { *(int4*)&ldsAlo[w0] = al0; *(int4*)&ldsAlo[w1] = al1; }
        *(int4*)&ldsBhi[w0] = bh0; *(int4*)&ldsBhi[w1] = bh1;
        *(int4*)&ldsBlo[w0] = bl0; *(int4*)&ldsBlo[w1] = bl1;
        __syncthreads();
        if (kt < 15) LOADK(kt + 1);
        short8v afh[4], afl[4], bfh[4], bfl[4];
        #pragma unroll
        for (int mi = 0; mi < 4; ++mi) {
            afh[mi] = *(const short8v*)&ldsAhi[((wm * 4 + mi) * 64 + lane) * 8];
            if constexpr (SPLIT_A)
                afl[mi] = *(const short8v*)&ldsAlo[((wm * 4 + mi) * 64 + lane) * 8];
        }
        #pragma unroll
        for (int ni = 0; ni < 4; ++ni) {
            bfh[ni] = *(const short8v*)&ldsBhi[((wn * 4 + ni) * 64 + lane) * 8];
            bfl[ni] = *(const short8v*)&ldsBlo[((wn * 4 + ni) * 64 + lane) * 8];
        }
        #pragma unroll
        for (int mi = 0; mi < 4; ++mi)
            #pragma unroll
            for (int ni = 0; ni < 4; ++ni) {
                MF(acc[mi][ni], afh[mi], bfh[ni]);
                MF(acc[mi][ni], afh[mi], bfl[ni]);
                if constexpr (SPLIT_A) MF(acc[mi][ni], afl[mi], bfh[ni]);
            }
    }
#undef LOADK
    #pragma unroll
    for (int mi = 0; mi < 4; ++mi) {
        #pragma unroll
        for (int ni = 0; ni < 4; ++ni) {
            int row = m0 + wm * 64 + mi * 16 + ((lane >> 4) << 2);
            int col = n0 + wn * 64 + ni * 16 + (lane & 15);
            float bv = bias ? bias[col] : 0.0f;
            #pragma unroll
            for (int r = 0; r < 4; ++r)
                C[(size_t)(row + r) * ldC + col] = acc[mi][ni][r] + bv;
        }
    }
}

template<bool SPLIT_A>
__global__ __launch_bounds__(256)
void gemm_one(const short* __restrict__ Ahi, const short* __restrict__ Alo,
              const short* __restrict__ Whi, const short* __restrict__ Wlo,
              const float* __restrict__ bias, float* __restrict__ C, int ntn) {
    __shared__ short lds[16384];
    int m0 = (blockIdx.x / ntn) * 128, n0 = (blockIdx.x % ntn) * 128;
    gemm_tile<SPLIT_A>(Ahi, Alo, Whi, Wlo, bias, C, m0, n0, ntn * 128, lds);
}

// ================= fused GRU step: GEMM + cell epilogue, no gate buffers =================
// State buffers A1[2048][1024] (h0 cols 0:512, h1 cols 512:1024), bf16 hi+lo, ping-pong.
// Part0 (blocks 0..255):   layer-0 step t=i   : gates = h0_old @ Whh0^T ; h0_new -> NEW
// Part1 (blocks 256..511): layer-1 step t=i-1 : r,z = [h0|h1]_old @ W1rz^T (K=1024),
//                          n = xn(K=512,Wnx over h0) + r*(hn(K=512,Wnh over h1))
// Block tile: 128 rows x 32 cols; 4 waves (64x16 each). LDS 28KB.
__global__ __launch_bounds__(256)
void fused_step(const short* __restrict__ OLDhi, const short* __restrict__ OLDlo,
                short* __restrict__ NEWhi, short* __restrict__ NEWlo,
                const short* __restrict__ W0hi, const short* __restrict__ W0lo,
                const short* __restrict__ Wrzhi, const short* __restrict__ Wrzlo,
                const short* __restrict__ Wnxhi, const short* __restrict__ Wnxlo,
                const short* __restrict__ Wnhhi, const short* __restrict__ Wnhlo,
                const float* __restrict__ xp0P, const float* __restrict__ bhh0,
                const float* __restrict__ bih1, const float* __restrict__ bhh1,
                short* __restrict__ sel_h, const int* __restrict__ startsP,
                const int* __restrict__ active, int i) {
    __shared__ short lds[14336];
    const int tid = threadIdx.x;
    const int bb = blockIdx.x;
    const int part = (bb >= 256);
    const int idx = bb & 255;
    const int js = idx >> 4, mb = idx & 15;   // blockIdx%8 == mb%8 -> same m-block on same XCD
    const int m0 = mb * 128, j0 = js * 32;
    const int wid = tid >> 6, lane = tid & 63;
    const int wm = wid >> 1, wn = wid & 1;

    short* ldsAhi = lds;
    short* ldsAlo = lds + 4096;
    short* ldsP   = lds + 8192;   // 6 panels x 1024 shorts: [gate*2+hl]

    // A staging (128x32 per K-tile): 2 int4/thread hi + 2 lo
    const int oiA0 = tid * 2, oiA1 = tid * 2 + 1;
    const int rA0 = oiA0 >> 2, cA0 = oiA0 & 3;
    const int rA1 = oiA1 >> 2, cA1 = oiA1 & 3;
    const int wA0 = ((rA0 >> 4) * 64 + (rA0 & 15) + (cA0 << 4)) * 8;
    const int wA1 = ((rA1 >> 4) * 64 + (rA1 & 15) + (cA1 << 4)) * 8;

    const short* aB0h = OLDhi + (size_t)(m0 + rA0) * 1024 + cA0 * 8;
    const short* aB1h = OLDhi + (size_t)(m0 + rA1) * 1024 + cA1 * 8;
    const short* aB0l = OLDlo + (size_t)(m0 + rA0) * 1024 + cA0 * 8;
    const short* aB1l = OLDlo + (size_t)(m0 + rA1) * 1024 + cA1 * 8;

    // panel staging metadata: 3 reps, 6 panels x 128 int4
    int wPq[3], pg[3], prw[3], poc[3];
    #pragma unroll
    for (int rep = 0; rep < 3; ++rep) {
        int id2 = rep * 256 + tid;
        int p = id2 >> 7, wi = id2 & 127;
        int prow = wi >> 2, poct = wi & 3;
        wPq[rep] = p * 1024 + ((prow >> 4) * 64 + (prow & 15) + (poct << 4)) * 8;
        pg[rep] = p; prw[rep] = prow; poc[rep] = poct;
    }

    const int col = j0 + wn * 16 + (lane & 15);

#define AFRAGS \
    short8v afh[4], afl[4]; \
    _Pragma("unroll") for (int mi = 0; mi < 4; ++mi) { \
        afh[mi] = *(const short8v*)&ldsAhi[((wm * 4 + mi) * 64 + lane) * 8]; \
        afl[mi] = *(const short8v*)&ldsAlo[((wm * 4 + mi) * 64 + lane) * 8]; }

#define GATEB(ACC, G) { \
    short8v bh = *(const short8v*)&ldsP[((G) * 2 + 0) * 1024 + (wn * 64 + lane) * 8]; \
    short8v bl = *(const short8v*)&ldsP[((G) * 2 + 1) * 1024 + (wn * 64 + lane) * 8]; \
    _Pragma("unroll") for (int mi = 0; mi < 4; ++mi) { \
        MF(ACC[mi], afh[mi], bh); MF(ACC[mi], afh[mi], bl); MF(ACC[mi], afl[mi], bh); } }

    if (part == 0) {
        const int act = active[i];
        if (m0 >= act) return;
        // panel sources: gate g rows g*512 + j0 + prow of W0 (stride 512)
        const short* pb[3];
        #pragma unroll
        for (int rep = 0; rep < 3; ++rep) {
            const short* W = (pg[rep] & 1) ? W0lo : W0hi;
            pb[rep] = W + (size_t)((pg[rep] >> 1) * 512 + j0 + prw[rep]) * 512 + poc[rep] * 8;
        }
        float4v aR[4] = {}, aZ[4] = {}, aN[4] = {};
        int4 s0, s1, s2, s3, q0, q1, q2;
        auto LOAD = [&](int kt) {
            int k0 = kt * 32;
            s0 = *(const int4*)(aB0h + k0); s1 = *(const int4*)(aB1h + k0);
            s2 = *(const int4*)(aB0l + k0); s3 = *(const int4*)(aB1l + k0);
            q0 = *(const int4*)(pb[0] + k0);
            q1 = *(const int4*)(pb[1] + k0);
            q2 = *(const int4*)(pb[2] + k0);
        };
        LOAD(0);
        for (int kt = 0; kt < 16; ++kt) {
            __syncthreads();
            *(int4*)&ldsAhi[wA0] = s0; *(int4*)&ldsAhi[wA1] = s1;
            *(int4*)&ldsAlo[wA0] = s2; *(int4*)&ldsAlo[wA1] = s3;
            *(int4*)&ldsP[wPq[0]] = q0; *(int4*)&ldsP[wPq[1]] = q1; *(int4*)&ldsP[wPq[2]] = q2;
            __syncthreads();
            if (kt < 15) LOAD(kt + 1);
            AFRAGS
            GATEB(aR, 0)
            GATEB(aZ, 1)
            GATEB(aN, 2)
        }
        const float b_r = bhh0[col], b_z = bhh0[512 + col], b_n = bhh0[1024 + col];
        #pragma unroll
        for (int mi = 0; mi < 4; ++mi) {
            int rowb = m0 + wm * 64 + mi * 16 + ((lane >> 4) << 2);
            #pragma unroll
            for (int r = 0; r < 4; ++r) {
                int row = rowb + r;
                float xr = xp0P[(size_t)row * H3 + col];
                float xz = xp0P[(size_t)row * H3 + 512 + col];
                float xn = xp0P[(size_t)row * H3 + 1024 + col];
                float rr = sigm(xr + aR[mi][r] + b_r);
                float zz = sigm(xz + aZ[mi][r] + b_z);
                float nn = tanhf(xn + rr * (aN[mi][r] + b_n));
                float hp = bf2f(OLDhi[(size_t)row * 1024 + col]) + bf2f(OLDlo[(size_t)row * 1024 + col]);
                float h = (1.0f - zz) * nn + zz * hp;
                short hh = f2bf(h);
                NEWhi[(size_t)row * 1024 + col] = hh;
                NEWlo[(size_t)row * 1024 + col] = f2bf(h - bf2f(hh));
            }
        }
    } else {
        if (i < 1) return;
        const int act = active[i - 1];
        if (m0 >= act) return;
        const int t = i - 1;
        // panel sources: r,z from Wrz (stride 1024, K=1024); n from Wnx (kt<16) / Wnh (kt>=16)
        const short* pbRZ[3]; const short* pbNx[3]; const short* pbNh[3]; int isn[3];
        #pragma unroll
        for (int rep = 0; rep < 3; ++rep) {
            int g = pg[rep] >> 1, hl = pg[rep] & 1;
            isn[rep] = (g == 2);
            const short* Wrz = hl ? Wrzlo : Wrzhi;
            const short* Wx  = hl ? Wnxlo : Wnxhi;
            const short* Wh  = hl ? Wnhlo : Wnhhi;
            pbRZ[rep] = Wrz + (size_t)(min(g, 1) * 512 + j0 + prw[rep]) * 1024 + poc[rep] * 8;
            pbNx[rep] = Wx + (size_t)(j0 + prw[rep]) * 512 + poc[rep] * 8;
            pbNh[rep] = Wh + (size_t)(j0 + prw[rep]) * 512 + poc[rep] * 8;
        }
        float4v aR[4] = {}, aZ[4] = {}, aXn[4] = {}, aHn[4] = {};
        int4 s0, s1, s2, s3, q0, q1, q2;
        auto LOAD = [&](int kt) {
            int k0 = kt * 32;
            s0 = *(const int4*)(aB0h + k0); s1 = *(const int4*)(aB1h + k0);
            s2 = *(const int4*)(aB0l + k0); s3 = *(const int4*)(aB1l + k0);
            q0 = *(const int4*)(isn[0] ? ((kt < 16) ? pbNx[0] + k0 : pbNh[0] + (k0 - 512)) : pbRZ[0] + k0);
            q1 = *(const int4*)(isn[1] ? ((kt < 16) ? pbNx[1] + k0 : pbNh[1] + (k0 - 512)) : pbRZ[1] + k0);
            q2 = *(const int4*)(isn[2] ? ((kt < 16) ? pbNx[2] + k0 : pbNh[2] + (k0 - 512)) : pbRZ[2] + k0);
        };
        LOAD(0);
        for (int kt = 0; kt < 16; ++kt) {
            __syncthreads();
            *(int4*)&ldsAhi[wA0] = s0; *(int4*)&ldsAhi[wA1] = s1;
            *(int4*)&ldsAlo[wA0] = s2; *(int4*)&ldsAlo[wA1] = s3;
            *(int4*)&ldsP[wPq[0]] = q0; *(int4*)&ldsP[wPq[1]] = q1; *(int4*)&ldsP[wPq[2]] = q2;
            __syncthreads();
            LOAD(kt + 1);
            AFRAGS
            GATEB(aR, 0)
            GATEB(aZ, 1)
            GATEB(aXn, 2)
        }
        for (int kt = 16; kt < 32; ++kt) {
            __syncthreads();
            *(int4*)&ldsAhi[wA0] = s0; *(int4*)&ldsAhi[wA1] = s1;
            *(int4*)&ldsAlo[wA0] = s2; *(int4*)&ldsAlo[wA1] = s3;
            *(int4*)&ldsP[wPq[0]] = q0; *(int4*)&ldsP[wPq[1]] = q1; *(int4*)&ldsP[wPq[2]] = q2;
            __syncthreads();
            if (kt < 31) LOAD(kt + 1);
            AFRAGS
            GATEB(aR, 0)
            GATEB(aZ, 1)
            GATEB(aHn, 2)
        }
        const float b_r = bih1[col] + bhh1[col];
        const float b_z = bih1[512 + col] + bhh1[512 + col];
        const float b_xn = bih1[1024 + col];
        const float b_hn = bhh1[1024 + col];
        #pragma unroll
        for (int mi = 0; mi < 4; ++mi) {
            int rowb = m0 + wm * 64 + mi * 16 + ((lane >> 4) << 2);
            #pragma unroll
            for (int r = 0; r < 4; ++r) {
                int row = rowb + r;
                float rr = sigm(aR[mi][r] + b_r);
                float zz = sigm(aZ[mi][r] + b_z);
                float nn = tanhf(aXn[mi][r] + b_xn + rr * (aHn[mi][r] + b_hn));
                float hp = bf2f(OLDhi[(size_t)row * 1024 + 512 + col]) + bf2f(OLDlo[(size_t)row * 1024 + 512 + col]);
                float h = (1.0f - zz) * nn + zz * hp;
                short hh = f2bf(h);
                NEWhi[(size_t)row * 1024 + 512 + col] = hh;
                NEWlo[(size_t)row * 1024 + 512 + col] = f2bf(h - bf2f(hh));
                if (row < act)
                    sel_h[((size_t)startsP[row] + t) * Hd + col] = f2bf(h);
            }
        }
    }
#undef AFRAGS
#undef GATEB
}

extern "C" void kernel_launch(void* const* d_in, const int* in_sizes, int n_in,
                              void* d_out, int out_size, void* d_ws, size_t ws_size,
                              hipStream_t stream) {
    (void)in_sizes; (void)n_in; (void)out_size; (void)ws_size;
    const float* x    = (const float*)d_in[0];
    const float* Wih0 = (const float*)d_in[1];
    const float* Whh0 = (const float*)d_in[2];
    const float* bih0 = (const float*)d_in[3];
    const float* bhh0 = (const float*)d_in[4];
    const float* Wih1 = (const float*)d_in[5];
    const float* Whh1 = (const float*)d_in[6];
    const float* bih1 = (const float*)d_in[7];
    const float* bhh1 = (const float*)d_in[8];
    const float* Wout = (const float*)d_in[9];
    const float* bout = (const float*)d_in[10];
    const int*   psi  = (const int*)d_in[11];
    float* out = (float*)d_out;

    char* p = (char*)d_ws;
    auto alloc = [&](size_t bytes) { char* r = p; p += (bytes + 255) & ~255ULL; return r; };
    short* xPhi   = (short*)alloc((size_t)Bn * Kd * 2);
    short* xPlo   = (short*)alloc((size_t)Bn * Kd * 2);
    short* Wih0hi = (short*)alloc((size_t)H3 * Kd * 2);
    short* Wih0lo = (short*)alloc((size_t)H3 * Kd * 2);
    short* W0hi   = (short*)alloc((size_t)H3 * Kd * 2);
    short* W0lo   = (short*)alloc((size_t)H3 * Kd * 2);
    short* Wrzhi  = (short*)alloc((size_t)1024 * 1024 * 2);
    short* Wrzlo  = (short*)alloc((size_t)1024 * 1024 * 2);
    short* Wnxhi  = (short*)alloc((size_t)512 * 512 * 2);
    short* Wnxlo  = (short*)alloc((size_t)512 * 512 * 2);
    short* Wnhhi  = (short*)alloc((size_t)512 * 512 * 2);
    short* Wnhlo  = (short*)alloc((size_t)512 * 512 * 2);
    short* Wouthi = (short*)alloc((size_t)OUTD * Kd * 2);
    short* Woutlo = (short*)alloc((size_t)OUTD * Kd * 2);
    float* xp0P   = (float*)alloc((size_t)Bn * H3 * 4);
    short* Aahi   = (short*)alloc((size_t)Bn * 1024 * 2);
    short* Aalo   = (short*)alloc((size_t)Bn * 1024 * 2);
    short* Abhi   = (short*)alloc((size_t)Bn * 1024 * 2);
    short* Ablo   = (short*)alloc((size_t)Bn * 1024 * 2);
    short* sel_h  = (short*)alloc((size_t)Nn * Hd * 2);
    int* perm     = (int*)alloc(Bn * 4);
    int* startsP  = (int*)alloc(Bn * 4);
    int* active   = (int*)alloc(64 * 4);

    prologue<<<1, 1024, 0, stream>>>(psi, perm, startsP, active);
    split_perm<<<1024, 256, 0, stream>>>(x, perm, xPhi, xPlo);
    split_kern<<<768, 256, 0, stream>>>(Wih0, Wih0hi, Wih0lo, H3 * Kd);
    split_kern<<<768, 256, 0, stream>>>(Whh0, W0hi, W0lo, H3 * Kd);
    pack_w1rz<<<1024, 256, 0, stream>>>(Wih1, Whh1, Wrzhi, Wrzlo);
    split_kern<<<256, 256, 0, stream>>>(Wih1 + (size_t)1024 * 512, Wnxhi, Wnxlo, 512 * 512);
    split_kern<<<256, 256, 0, stream>>>(Whh1 + (size_t)1024 * 512, Wnhhi, Wnhlo, 512 * 512);
    split_kern<<<128, 256, 0, stream>>>(Wout, Wouthi, Woutlo, OUTD * Kd);
    zero4<<<2048, 256, 0, stream>>>(Aahi, Aalo, Abhi, Ablo, Bn * 1024);

    gemm_one<true><<<192, 256, 0, stream>>>(xPhi, xPlo, Wih0hi, Wih0lo, bih0, xp0P, 12);

    for (int i = 0; i <= TMAX; ++i) {
        const short* OLDhi = (i & 1) ? Abhi : Aahi;
        const short* OLDlo = (i & 1) ? Ablo : Aalo;
        short* NEWhi = (i & 1) ? Aahi : Abhi;
        short* NEWlo = (i & 1) ? Aalo : Ablo;
        fused_step<<<512, 256, 0, stream>>>(OLDhi, OLDlo, NEWhi, NEWlo,
                                            W0hi, W0lo, Wrzhi, Wrzlo,
                                            Wnxhi, Wnxlo, Wnhhi, Wnhlo,
                                            xp0P, bhh0, bih1, bhh1,
                                            sel_h, startsP, active, i);
    }

    gemm_one<false><<<512, 256, 0, stream>>>(sel_h, nullptr, Wouthi, Woutlo, bout, out, 2);
}